// Round 1
// baseline (895.952 us; speedup 1.0000x reference)
//
#include <hip/hip_runtime.h>
#include <math.h>

#define BB 2
#define CC 192
#define NH 4
#define CH 48
#define SRCP 16
#define HH 256
#define WW 256
#define NPIX (HH*WW)

static __device__ __forceinline__ unsigned short f2bf(float f) {
    union { float f; unsigned int u; } c; c.f = f;
    unsigned int r = c.u + 0x7fffu + ((c.u >> 16) & 1u);
    return (unsigned short)(r >> 16);
}

template<int CTRL>
static __device__ __forceinline__ float dpp_add(float v) {
    int t = __builtin_amdgcn_update_dpp(0, __float_as_int(v), CTRL, 0xf, 0xf, true);
    return v + __int_as_float(t);
}

// K1: depthwise 3x3 conv for one (b, head, row). q,k -> LDS (bf16 pairs),
// v -> global ws (bf16). Then per-channel sumsq(q,k) and partial S = q k^T
// over this row's 256 pixels, reduced with DPP row_shr (rows of 16 = the 16
// n-subsets), atomically added to global S.
__global__ __launch_bounds__(256, 2) void k_conv(
    const float* __restrict__ x, const float* __restrict__ wqkv,
    unsigned short* __restrict__ vws, float* __restrict__ Sws,
    float* __restrict__ sqws)
{
    __shared__ float wlds[3*CH*9];            // 5184 B
    __shared__ unsigned int qk32[2][CH][130]; // 49920 B; 128 bf16-pairs + pad

    const int tid = threadIdx.x;
    const int y  = blockIdx.x;
    const int hd = blockIdx.y;
    const int b  = blockIdx.z;

    for (int i = tid; i < 3*CH*9; i += 256) {
        int type = i / (CH*9);
        int rem  = i - type*(CH*9);
        wlds[i] = wqkv[type*(CC*9) + hd*(CH*9) + rem];
    }
    __syncthreads();

    {
        const int xp = tid;
        const int y0 = (y > 0) ? (y-1) : 0;
        const int y2 = (y < HH-1) ? (y+1) : y;
        const int xl = (xp > 0) ? (xp-1) : 0;
        const int xr = (xp < WW-1) ? (xp+1) : xp;
        const float my0 = (y > 0) ? 1.f : 0.f;
        const float my2 = (y < HH-1) ? 1.f : 0.f;
        const float mx0 = (xp > 0) ? 1.f : 0.f;
        const float mx2 = (xp < WW-1) ? 1.f : 0.f;
        const float m00 = my0*mx0, m02 = my0*mx2, m20 = my2*mx0, m22 = my2*mx2;

        #pragma unroll
        for (int type = 0; type < 3; ++type) {
            const int srcbase = type*64 + SRCP*hd;
            const float* wt = &wlds[type*(CH*9)];
            for (int g = 0; g < SRCP; ++g) {
                const float* base = x + ((size_t)(b*CC + srcbase + g)*HH)*WW;
                const float* r0 = base + (size_t)y0*WW;
                const float* r1 = base + (size_t)y *WW;
                const float* r2 = base + (size_t)y2*WW;
                float a00 = r0[xl]*m00, a01 = r0[xp]*my0, a02 = r0[xr]*m02;
                float a10 = r1[xl]*mx0, a11 = r1[xp],     a12 = r1[xr]*mx2;
                float a20 = r2[xl]*m20, a21 = r2[xp]*my2, a22 = r2[xr]*m22;
                #pragma unroll
                for (int r = 0; r < 3; ++r) {
                    const int cl = 3*g + r;
                    const float* w = wt + cl*9;
                    float val = a00*w[0] + a01*w[1] + a02*w[2]
                              + a10*w[3] + a11*w[4] + a12*w[5]
                              + a20*w[6] + a21*w[7] + a22*w[8];
                    if (type == 2) {
                        vws[(size_t)(b*CC + hd*CH + cl)*NPIX + y*WW + xp] = f2bf(val);
                    } else {
                        ((unsigned short*)&qk32[type][cl][0])[xp] = f2bf(val);
                    }
                }
            }
        }
    }
    __syncthreads();

    if (tid < 2*CH) {
        const int which = tid / CH;
        const int cl = tid - which*CH;
        const unsigned int* row = &qk32[which][cl][0];
        float ssum = 0.f;
        for (int j = 0; j < WW/2; ++j) {
            unsigned int u = row[j];
            float lo = __uint_as_float(u << 16);
            float hi = __uint_as_float(u & 0xffff0000u);
            ssum = fmaf(lo, lo, ssum);
            ssum = fmaf(hi, hi, ssum);
        }
        atomicAdd(&sqws[((b*NH + hd)*2 + which)*CH + cl], ssum);
    }

    {
        const int s   = tid & 15;   // n-subset (pairs s, 16+s, ..., 112+s)
        const int tau = tid >> 4;   // 12x12 tile id; tau == DPP row
        const int c0 = (tau & 3) * 12;
        const int d0 = (tau >> 2) * 12;
        float acc[12][12];
        #pragma unroll
        for (int i = 0; i < 12; ++i)
            #pragma unroll
            for (int j = 0; j < 12; ++j) acc[i][j] = 0.f;

        for (int p = 0; p < 8; ++p) {
            const int P = p*16 + s;
            const unsigned int* bq = &qk32[0][c0][P];
            const unsigned int* bk = &qk32[1][d0][P];
            float ql[12], qh[12], kl[12], kh[12];
            #pragma unroll
            for (int i = 0; i < 12; ++i) {
                unsigned int u = bq[i*130];
                ql[i] = __uint_as_float(u << 16);
                qh[i] = __uint_as_float(u & 0xffff0000u);
            }
            #pragma unroll
            for (int j = 0; j < 12; ++j) {
                unsigned int u = bk[j*130];
                kl[j] = __uint_as_float(u << 16);
                kh[j] = __uint_as_float(u & 0xffff0000u);
            }
            #pragma unroll
            for (int i = 0; i < 12; ++i)
                #pragma unroll
                for (int j = 0; j < 12; ++j)
                    acc[i][j] = fmaf(ql[i], kl[j], fmaf(qh[i], kh[j], acc[i][j]));
        }

        #pragma unroll
        for (int i = 0; i < 12; ++i)
            #pragma unroll
            for (int j = 0; j < 12; ++j) {
                float v = acc[i][j];
                v = dpp_add<0x111>(v);  // row_shr:1
                v = dpp_add<0x112>(v);  // row_shr:2
                v = dpp_add<0x114>(v);  // row_shr:4
                v = dpp_add<0x118>(v);  // row_shr:8 -> lane s==15 holds row sum
                acc[i][j] = v;
            }
        if (s == 15) {
            float* Sbase = Sws + ((size_t)(b*NH + hd)*CH + c0)*CH + d0;
            #pragma unroll
            for (int i = 0; i < 12; ++i)
                #pragma unroll
                for (int j = 0; j < 12; ++j)
                    atomicAdd(Sbase + i*CH + j, acc[i][j]);
        }
    }
}

// K2: one block per (b,head): norms -> logits -> softmax -> W2T[b][dg][o]
__global__ __launch_bounds__(256) void k_attn(
    const float* __restrict__ Sws, const float* __restrict__ sqws,
    const float* __restrict__ temp, const float* __restrict__ wproj,
    float* __restrict__ W2T)
{
    __shared__ float att[CH][CH+1];
    __shared__ float wp[CC][CH+1];
    __shared__ float nrm[2][CH];

    const int tid = threadIdx.x;
    const int b  = blockIdx.x >> 2;
    const int hd = blockIdx.x & 3;

    if (tid < 2*CH) {
        int which = tid / CH, cl = tid - which*CH;
        nrm[which][cl] = fmaxf(sqrtf(sqws[((b*NH + hd)*2 + which)*CH + cl]), 1e-12f);
    }
    __syncthreads();

    const float tscale = temp[hd];
    for (int m = tid; m < CH*CH; m += 256) {
        int c = m / CH, d = m - c*CH;
        att[c][d] = Sws[((size_t)(b*NH + hd)*CH + c)*CH + d] * tscale
                    / (nrm[0][c] * nrm[1][d]);
    }
    __syncthreads();

    if (tid < CH) {
        float mx = -1e30f;
        for (int d = 0; d < CH; ++d) mx = fmaxf(mx, att[tid][d]);
        float sm = 0.f;
        for (int d = 0; d < CH; ++d) { float e = expf(att[tid][d] - mx); att[tid][d] = e; sm += e; }
        float inv = 1.f / sm;
        for (int d = 0; d < CH; ++d) att[tid][d] *= inv;
    }

    for (int m = tid; m < CC*CH; m += 256) {
        int o = m / CH, il = m - o*CH;
        wp[o][il] = wproj[o*CC + hd*CH + il];
    }
    __syncthreads();

    const int o0  = (tid & 31) * 6;
    const int dl0 = (tid >> 5) * 6;
    float a[6][6];
    #pragma unroll
    for (int i = 0; i < 6; ++i)
        #pragma unroll
        for (int j = 0; j < 6; ++j) a[i][j] = 0.f;
    for (int il = 0; il < CH; ++il) {
        float wv[6], av[6];
        #pragma unroll
        for (int i = 0; i < 6; ++i) wv[i] = wp[o0+i][il];
        #pragma unroll
        for (int j = 0; j < 6; ++j) av[j] = att[il][dl0+j];
        #pragma unroll
        for (int i = 0; i < 6; ++i)
            #pragma unroll
            for (int j = 0; j < 6; ++j)
                a[i][j] = fmaf(wv[i], av[j], a[i][j]);
    }
    #pragma unroll
    for (int j = 0; j < 6; ++j)
        #pragma unroll
        for (int i = 0; i < 6; ++i)
            W2T[((size_t)(b*CC) + hd*CH + dl0 + j)*CC + o0 + i] = a[i][j];
}

// K3: out[b][o][n] = sum_dg W2T[b][dg][o] * v[b][dg][n]
// One wave = 48 output channels x 64 pixels; W2 rows are wave-uniform -> s_load.
__global__ __launch_bounds__(256, 4) void k_out(
    const unsigned short* __restrict__ vws, const float* __restrict__ W2T,
    float* __restrict__ out)
{
    const int lane = threadIdx.x & 63;
    const int wv = __builtin_amdgcn_readfirstlane(threadIdx.x >> 6);
    const int n = blockIdx.x * 64 + lane;
    const int b = blockIdx.y;
    const int och0 = wv * CH;
    const unsigned short* vp = vws + (size_t)(b*CC)*NPIX + n;
    const float* wbase = W2T + (size_t)(b*CC)*CC + och0;
    float acc[CH];
    #pragma unroll
    for (int o = 0; o < CH; ++o) acc[o] = 0.f;
    for (int dg = 0; dg < CC; ++dg) {
        float vv = __uint_as_float(((unsigned int)vp[(size_t)dg*NPIX]) << 16);
        const float* wr = wbase + dg*CC;
        #pragma unroll
        for (int o = 0; o < CH; ++o) acc[o] = fmaf(wr[o], vv, acc[o]);
    }
    float* op = out + ((size_t)(b*CC + och0))*NPIX + n;
    #pragma unroll
    for (int o = 0; o < CH; ++o) op[(size_t)o*NPIX] = acc[o];
}

extern "C" void kernel_launch(void* const* d_in, const int* in_sizes, int n_in,
                              void* d_out, int out_size, void* d_ws, size_t ws_size,
                              hipStream_t stream)
{
    const float* x     = (const float*)d_in[0];
    const float* wqkv  = (const float*)d_in[1];
    const float* temp  = (const float*)d_in[2];
    const float* wproj = (const float*)d_in[3];
    float* out = (float*)d_out;
    (void)in_sizes; (void)n_in; (void)out_size; (void)ws_size;

    unsigned short* vws = (unsigned short*)d_ws;                 // 50,331,648 B (bf16 v)
    const size_t VBYTES = (size_t)BB*CC*NPIX*sizeof(unsigned short);
    float* Sws  = (float*)((char*)d_ws + VBYTES);                // 18432 f
    float* sqws = Sws + (size_t)BB*NH*CH*CH;                     // 768 f
    float* W2T  = sqws + (size_t)BB*NH*2*CH;                     // 73728 f

    hipMemsetAsync(Sws, 0, (size_t)(BB*NH*CH*CH + BB*NH*2*CH)*sizeof(float), stream);
    k_conv<<<dim3(HH, NH, BB), 256, 0, stream>>>(x, wqkv, vws, Sws, sqws);
    k_attn<<<dim3(BB*NH), 256, 0, stream>>>(Sws, sqws, temp, wproj, W2T);
    k_out<<<dim3(NPIX/64, BB), 256, 0, stream>>>(vws, W2T, out);
}

// Round 2
// 321.919 us; speedup vs baseline: 2.7832x; 2.7832x over previous
//
#include <hip/hip_runtime.h>
#include <math.h>

#define BB 2
#define CC 192
#define NH 4
#define CH 48
#define SRCP 16
#define HH 256
#define WW 256
#define NPIX (HH*WW)

typedef __attribute__((ext_vector_type(8))) short short8;   // 8 bf16 = 4 VGPR
typedef __attribute__((ext_vector_type(4))) float f4;

static __device__ __forceinline__ unsigned short f2bf(float f) {
    union { float f; unsigned int u; } c; c.f = f;
    unsigned int r = c.u + 0x7fffu + ((c.u >> 16) & 1u);
    return (unsigned short)(r >> 16);
}

// K1: depthwise 3x3 conv for one (b, head, row). q,k -> LDS bf16 rows [c][256]
// (132-dword stride: 16B aligned, 2-way banks = free). v -> global ws in
// [n][dg] layout (bf16, packed dwordx4 stores). Then sumsq(q,k) and
// S += q k^T via MFMA 16x16x32 bf16 (9 tiles x 8 K-steps over 4 waves),
// accumulated to global S with atomics.
__global__ __launch_bounds__(256, 2) void k_conv(
    const float* __restrict__ x, const float* __restrict__ wqkv,
    unsigned short* __restrict__ vws, float* __restrict__ Sws,
    float* __restrict__ sqws)
{
    __shared__ float wlds[3*CH*9];            // 5184 B
    __shared__ unsigned int qk32[2][CH][132]; // 50688 B

    const int tid = threadIdx.x;
    const int hd = blockIdx.x;
    const int y  = blockIdx.y;
    const int b  = blockIdx.z;

    for (int i = tid; i < 3*CH*9; i += 256) {
        int type = i / (CH*9);
        int rem  = i - type*(CH*9);
        wlds[i] = wqkv[type*(CC*9) + hd*(CH*9) + rem];
    }
    __syncthreads();

    {
        const int xp = tid;
        const int y0 = (y > 0) ? (y-1) : 0;
        const int y2 = (y < HH-1) ? (y+1) : y;
        const int xl = (xp > 0) ? (xp-1) : 0;
        const int xr = (xp < WW-1) ? (xp+1) : xp;
        const float my0 = (y > 0) ? 1.f : 0.f;
        const float my2 = (y < HH-1) ? 1.f : 0.f;
        const float mx0 = (xp > 0) ? 1.f : 0.f;
        const float mx2 = (xp < WW-1) ? 1.f : 0.f;
        const float m00 = my0*mx0, m02 = my0*mx2, m20 = my2*mx0, m22 = my2*mx2;

        // types 0 (q) and 1 (k) -> LDS
        #pragma unroll
        for (int type = 0; type < 2; ++type) {
            const int srcbase = type*64 + SRCP*hd;
            const float* wt = &wlds[type*(CH*9)];
            for (int g = 0; g < SRCP; ++g) {
                const float* base = x + ((size_t)(b*CC + srcbase + g)*HH)*WW;
                const float* r0 = base + (size_t)y0*WW;
                const float* r1 = base + (size_t)y *WW;
                const float* r2 = base + (size_t)y2*WW;
                float a00 = r0[xl]*m00, a01 = r0[xp]*my0, a02 = r0[xr]*m02;
                float a10 = r1[xl]*mx0, a11 = r1[xp],     a12 = r1[xr]*mx2;
                float a20 = r2[xl]*m20, a21 = r2[xp]*my2, a22 = r2[xr]*m22;
                #pragma unroll
                for (int r = 0; r < 3; ++r) {
                    const int cl = 3*g + r;
                    const float* w = wt + cl*9;
                    float val = a00*w[0] + a01*w[1] + a02*w[2]
                              + a10*w[3] + a11*w[4] + a12*w[5]
                              + a20*w[6] + a21*w[7] + a22*w[8];
                    ((unsigned short*)&qk32[type][cl][0])[xp] = f2bf(val);
                }
            }
        }

        // type 2 (v): fully unrolled so vpack[] stays in registers
        unsigned int vpack[24];
        {
            const int srcbase = 128 + SRCP*hd;
            const float* wt = &wlds[2*(CH*9)];
            #pragma unroll
            for (int g = 0; g < SRCP; ++g) {
                const float* base = x + ((size_t)(b*CC + srcbase + g)*HH)*WW;
                const float* r0 = base + (size_t)y0*WW;
                const float* r1 = base + (size_t)y *WW;
                const float* r2 = base + (size_t)y2*WW;
                float a00 = r0[xl]*m00, a01 = r0[xp]*my0, a02 = r0[xr]*m02;
                float a10 = r1[xl]*mx0, a11 = r1[xp],     a12 = r1[xr]*mx2;
                float a20 = r2[xl]*m20, a21 = r2[xp]*my2, a22 = r2[xr]*m22;
                #pragma unroll
                for (int r = 0; r < 3; ++r) {
                    const int cl = 3*g + r;
                    const float* w = wt + cl*9;
                    float val = a00*w[0] + a01*w[1] + a02*w[2]
                              + a10*w[3] + a11*w[4] + a12*w[5]
                              + a20*w[6] + a21*w[7] + a22*w[8];
                    unsigned int u = f2bf(val);
                    if (cl & 1) vpack[cl >> 1] |= (u << 16);
                    else        vpack[cl >> 1]  = u;
                }
            }
        }
        // write v: [b][n][dg] layout, 6 x dwordx4 (16B each, 384B row stride)
        {
            unsigned short* vp = vws + ((size_t)b*NPIX + (size_t)y*WW + xp)*CC + hd*CH;
            #pragma unroll
            for (int st = 0; st < 6; ++st) {
                uint4 u; u.x = vpack[st*4+0]; u.y = vpack[st*4+1];
                         u.z = vpack[st*4+2]; u.w = vpack[st*4+3];
                *(uint4*)(vp + st*8) = u;
            }
        }
    }
    __syncthreads();

    // per-channel sum of squares for q,k norms
    if (tid < 2*CH) {
        const int which = tid / CH;
        const int cl = tid - which*CH;
        const uint4* row = (const uint4*)&qk32[which][cl][0];
        float ssum = 0.f;
        for (int j = 0; j < 32; ++j) {
            uint4 u = row[j];
            #pragma unroll
            for (int q4 = 0; q4 < 4; ++q4) {
                unsigned int w = (&u.x)[q4];
                float lo = __uint_as_float(w << 16);
                float hi = __uint_as_float(w & 0xffff0000u);
                ssum = fmaf(lo, lo, ssum);
                ssum = fmaf(hi, hi, ssum);
            }
        }
        atomicAdd(&sqws[((b*NH + hd)*2 + which)*CH + cl], ssum);
    }

    // S = q k^T via MFMA: A[m=c][k=n], B[k=n][nn=d]; both frags read 8
    // consecutive bf16 from a channel row at n = ks*32 + quad*8.
    {
        const int lane = tid & 63;
        const int wv = tid >> 6;
        const int m = lane & 15, quad = lane >> 4;
        for (int p = wv; p < 9; p += 4) {
            const int ct = p / 3, dt = p - ct*3;
            f4 acc = {0.f, 0.f, 0.f, 0.f};
            const char* qbase = (const char*)&qk32[0][ct*16 + m][0] + quad*16;
            const char* kbase = (const char*)&qk32[1][dt*16 + m][0] + quad*16;
            #pragma unroll
            for (int ks = 0; ks < 8; ++ks) {
                short8 afr = *(const short8*)(qbase + ks*64);
                short8 bfr = *(const short8*)(kbase + ks*64);
                acc = __builtin_amdgcn_mfma_f32_16x16x32_bf16(afr, bfr, acc, 0, 0, 0);
            }
            const int c0 = ct*16 + quad*4, d = dt*16 + m;
            float* Sp = Sws + ((size_t)(b*NH + hd)*CH + c0)*CH + d;
            #pragma unroll
            for (int r = 0; r < 4; ++r) atomicAdd(Sp + r*CH, acc[r]);
        }
    }
}

// K2: one block per (b,head): norms -> logits -> softmax -> W2 = wproj*attn,
// exported bf16 in [o][dg] (A-operand-ready) layout.
__global__ __launch_bounds__(256) void k_attn(
    const float* __restrict__ Sws, const float* __restrict__ sqws,
    const float* __restrict__ temp, const float* __restrict__ wproj,
    unsigned short* __restrict__ W2bf)
{
    __shared__ float att[CH][CH+1];
    __shared__ float wp[CC][CH+1];
    __shared__ float nrm[2][CH];

    const int tid = threadIdx.x;
    const int b  = blockIdx.x >> 2;
    const int hd = blockIdx.x & 3;

    if (tid < 2*CH) {
        int which = tid / CH, cl = tid - which*CH;
        nrm[which][cl] = fmaxf(sqrtf(sqws[((b*NH + hd)*2 + which)*CH + cl]), 1e-12f);
    }
    __syncthreads();

    const float tscale = temp[hd];
    for (int m = tid; m < CH*CH; m += 256) {
        int c = m / CH, d = m - c*CH;
        att[c][d] = Sws[((size_t)(b*NH + hd)*CH + c)*CH + d] * tscale
                    / (nrm[0][c] * nrm[1][d]);
    }
    __syncthreads();

    if (tid < CH) {
        float mx = -1e30f;
        for (int d = 0; d < CH; ++d) mx = fmaxf(mx, att[tid][d]);
        float sm = 0.f;
        for (int d = 0; d < CH; ++d) { float e = expf(att[tid][d] - mx); att[tid][d] = e; sm += e; }
        float inv = 1.f / sm;
        for (int d = 0; d < CH; ++d) att[tid][d] *= inv;
    }

    for (int m = tid; m < CC*CH; m += 256) {
        int o = m / CH, il = m - o*CH;
        wp[o][il] = wproj[o*CC + hd*CH + il];
    }
    __syncthreads();

    const int o0  = (tid & 31) * 6;
    const int dl0 = (tid >> 5) * 6;
    float a[6][6];
    #pragma unroll
    for (int i = 0; i < 6; ++i)
        #pragma unroll
        for (int j = 0; j < 6; ++j) a[i][j] = 0.f;
    for (int il = 0; il < CH; ++il) {
        float wv[6], av[6];
        #pragma unroll
        for (int i = 0; i < 6; ++i) wv[i] = wp[o0+i][il];
        #pragma unroll
        for (int j = 0; j < 6; ++j) av[j] = att[il][dl0+j];
        #pragma unroll
        for (int i = 0; i < 6; ++i)
            #pragma unroll
            for (int j = 0; j < 6; ++j)
                a[i][j] = fmaf(wv[i], av[j], a[i][j]);
    }
    #pragma unroll
    for (int i = 0; i < 6; ++i)
        #pragma unroll
        for (int j = 0; j < 6; ++j)
            W2bf[((size_t)b*CC + o0 + i)*CC + hd*CH + dl0 + j] = f2bf(a[i][j]);
}

// K3: out[b][o][n] = sum_dg W2[o][dg] v[n][dg]  — MFMA GEMM.
// Block: M=192 x N=128, 4 waves in 2x2 (M-half x N-half). A from LDS-staged
// bf16 W2, B straight from global v (16B loads at 64B granularity).
__global__ __launch_bounds__(256, 2) void k_out(
    const unsigned short* __restrict__ vws, const unsigned short* __restrict__ W2bf,
    float* __restrict__ out)
{
    __shared__ unsigned short w2l[CC][200];   // 76800 B; stride 400B: aligned, 2-way banks

    const int tid = threadIdx.x;
    const int b  = blockIdx.y;
    const int n0 = blockIdx.x * 128;

    {
        const uint4* src = (const uint4*)(W2bf + (size_t)b*CC*CC);
        for (int i = tid; i < CC*24; i += 256) {
            int o = i / 24, c = i - o*24;
            *(uint4*)&w2l[o][c*8] = src[i];
        }
    }
    __syncthreads();

    const int lane = tid & 63;
    const int wv = tid >> 6;
    const int m0  = (wv & 1) * 96;
    const int nn0 = (wv >> 1) * 64;
    const int m = lane & 15, quad = lane >> 4;

    f4 acc[6][4];
    #pragma unroll
    for (int mt = 0; mt < 6; ++mt)
        #pragma unroll
        for (int nt = 0; nt < 4; ++nt) acc[mt][nt] = (f4){0.f, 0.f, 0.f, 0.f};

    const unsigned short* vb = vws + ((size_t)b*NPIX + n0 + nn0 + m)*CC + quad*8;

    #pragma unroll
    for (int ks = 0; ks < 6; ++ks) {
        short8 bfr[4];
        #pragma unroll
        for (int nt = 0; nt < 4; ++nt)
            bfr[nt] = *(const short8*)(vb + (size_t)(nt*16)*CC + ks*32);
        short8 afr[6];
        #pragma unroll
        for (int mt = 0; mt < 6; ++mt)
            afr[mt] = *(const short8*)&w2l[m0 + mt*16 + m][ks*32 + quad*8];
        #pragma unroll
        for (int mt = 0; mt < 6; ++mt)
            #pragma unroll
            for (int nt = 0; nt < 4; ++nt)
                acc[mt][nt] = __builtin_amdgcn_mfma_f32_16x16x32_bf16(afr[mt], bfr[nt], acc[mt][nt], 0, 0, 0);
    }

    #pragma unroll
    for (int mt = 0; mt < 6; ++mt) {
        const int o = m0 + mt*16 + quad*4;
        #pragma unroll
        for (int nt = 0; nt < 4; ++nt) {
            const int px = n0 + nn0 + nt*16 + m;
            float* op = out + ((size_t)(b*CC + o))*NPIX + px;
            #pragma unroll
            for (int r = 0; r < 4; ++r) op[(size_t)r*NPIX] = acc[mt][nt][r];
        }
    }
}

extern "C" void kernel_launch(void* const* d_in, const int* in_sizes, int n_in,
                              void* d_out, int out_size, void* d_ws, size_t ws_size,
                              hipStream_t stream)
{
    const float* x     = (const float*)d_in[0];
    const float* wqkv  = (const float*)d_in[1];
    const float* temp  = (const float*)d_in[2];
    const float* wproj = (const float*)d_in[3];
    float* out = (float*)d_out;
    (void)in_sizes; (void)n_in; (void)out_size; (void)ws_size;

    unsigned short* vws = (unsigned short*)d_ws;                 // [b][n][dg] bf16: 50,331,648 B
    const size_t VBYTES = (size_t)BB*CC*NPIX*sizeof(unsigned short);
    float* Sws  = (float*)((char*)d_ws + VBYTES);                // 18432 f
    float* sqws = Sws + (size_t)BB*NH*CH*CH;                     // 768 f
    unsigned short* W2bf = (unsigned short*)(sqws + (size_t)BB*NH*2*CH); // 73728 u16

    hipMemsetAsync(Sws, 0, (size_t)(BB*NH*CH*CH + BB*NH*2*CH)*sizeof(float), stream);
    k_conv<<<dim3(NH, HH, BB), 256, 0, stream>>>(x, wqkv, vws, Sws, sqws);
    k_attn<<<dim3(BB*NH), 256, 0, stream>>>(Sws, sqws, temp, wproj, W2bf);
    k_out<<<dim3(NPIX/128, BB), 256, 0, stream>>>(vws, W2bf, out);
}